// Round 1
// baseline (8207.233 us; speedup 1.0000x reference)
//
#include <hip/hip_runtime.h>

// LSTM_26877905338550 — B=1048576 independent tiny-MLP LSTM chains, T=3.
// Compute-bound on f32 VALU (~30k FMA/elem). Strategy:
//  - prep kernel packs/fuses weights into d_ws (W0' = W0L+W0R, p = p2@p1),
//    rows padded for 16B alignment
//  - main kernel: 1 thread = 1 element, all loops fully unrolled so weight
//    offsets are compile-time constants -> uniform scalar loads (s_load),
//    activations via native v_exp_f32 / v_rcp_f32.

#define NB 1048576

// packed weight offsets (floats), all 16B aligned
#define OWX   0      // Wx   [30][8]
#define OWH   240    // Wh   [30][32] (30 used)
#define OHTB  1200   // ht_b [32]
#define OW0   1232   // W0'  [30][32]
#define OB0   2192   // b0   [32]
#define OW1   2224   // W1   [45][32]
#define OB1   3664   // b1   [48]
#define OW2   3712   // W2   [40][48] (45 used)
#define OB2   5632   // b2   [40]
#define OW3   5672   // W3   [30][40]
#define OB3   6872   // b3   [32]
#define OGW   6904   // gW   [120][32] (30 used)
#define OGB   10744  // gb   [120]
#define OPW   10864  // pW   [32]  (p2@p1 fused)
#define OPB   10896  // pb   scalar

__global__ void prep_kernel(const float* __restrict__ htW, const float* __restrict__ htb,
                            const float* __restrict__ w0,  const float* __restrict__ b0,
                            const float* __restrict__ w1,  const float* __restrict__ b1,
                            const float* __restrict__ w2,  const float* __restrict__ b2,
                            const float* __restrict__ w3,  const float* __restrict__ b3,
                            const float* __restrict__ gw,  const float* __restrict__ gb,
                            const float* __restrict__ p1w, const float* __restrict__ p1b,
                            const float* __restrict__ p2w, const float* __restrict__ p2b,
                            float* __restrict__ ws) {
  int tid = threadIdx.x;
  for (int i = tid; i < 240; i += 256) {            // Wx [30][8]
    int j = i >> 3, k = i & 7;
    ws[OWX + i] = htW[j * 38 + k];
  }
  for (int i = tid; i < 960; i += 256) {            // Wh [30][32]
    int j = i >> 5, k = i & 31;
    ws[OWH + i] = (k < 30) ? htW[j * 38 + 8 + k] : 0.f;
  }
  for (int i = tid; i < 32; i += 256) ws[OHTB + i] = (i < 30) ? htb[i] : 0.f;
  for (int i = tid; i < 960; i += 256) {            // W0' = W0[:, :30] + W0[:, 30:]
    int j = i >> 5, k = i & 31;
    ws[OW0 + i] = (k < 30) ? (w0[j * 60 + k] + w0[j * 60 + 30 + k]) : 0.f;
  }
  for (int i = tid; i < 32; i += 256) ws[OB0 + i] = (i < 30) ? b0[i] : 0.f;
  for (int i = tid; i < 1440; i += 256) {           // W1 [45][32]
    int j = i >> 5, k = i & 31;
    ws[OW1 + i] = (k < 30) ? w1[j * 30 + k] : 0.f;
  }
  for (int i = tid; i < 48; i += 256) ws[OB1 + i] = (i < 45) ? b1[i] : 0.f;
  for (int i = tid; i < 1920; i += 256) {           // W2 [40][48]
    int j = i / 48, k = i % 48;
    ws[OW2 + i] = (k < 45) ? w2[j * 45 + k] : 0.f;
  }
  for (int i = tid; i < 40; i += 256) ws[OB2 + i] = b2[i];
  for (int i = tid; i < 1200; i += 256) {           // W3 [30][40]
    int j = i / 40, k = i % 40;
    ws[OW3 + i] = w3[j * 40 + k];
  }
  for (int i = tid; i < 32; i += 256) ws[OB3 + i] = (i < 30) ? b3[i] : 0.f;
  for (int i = tid; i < 3840; i += 256) {           // gW [120][32]
    int j = i >> 5, k = i & 31;
    ws[OGW + i] = (k < 30) ? gw[j * 30 + k] : 0.f;
  }
  for (int i = tid; i < 120; i += 256) ws[OGB + i] = gb[i];
  for (int i = tid; i < 32; i += 256) {             // pW = p2W @ p1W
    float acc = 0.f;
    if (i < 30)
      for (int m = 0; m < 10; m++) acc += p2w[m] * p1w[m * 30 + i];
    ws[OPW + i] = acc;
  }
  if (tid == 0) {
    float acc = p2b[0];
    for (int m = 0; m < 10; m++) acc += p2w[m] * p1b[m];
    ws[OPB] = acc;
  }
}

__device__ __forceinline__ float ftanh(float v) {
  // tanh(x) = 1 - 2/(exp2(2x*log2e)+1); saturates correctly via inf/0
  float u = __builtin_amdgcn_exp2f(v * 2.8853900817779268f);
  return 1.0f - 2.0f * __builtin_amdgcn_rcpf(u + 1.0f);
}
__device__ __forceinline__ float fsigm(float v) {
  float u = __builtin_amdgcn_exp2f(v * -1.4426950408889634f);
  return __builtin_amdgcn_rcpf(1.0f + u);
}

__global__ __launch_bounds__(256, 2) void lstm_main(const float* __restrict__ x,
                                                    const float* __restrict__ w,
                                                    float* __restrict__ out) {
  int b = blockIdx.x * 256 + threadIdx.x;
  float hidden[30], cell[30];
#pragma unroll
  for (int j = 0; j < 30; j++) { hidden[j] = 0.f; cell[j] = 0.f; }

  const float* xb = x + (size_t)b * 24;

  for (int t = 0; t < 3; t++) {
    float4 xa = *(const float4*)(xb + t * 8);
    float4 xc = *(const float4*)(xb + t * 8 + 4);
    float xr[8] = {xa.x, xa.y, xa.z, xa.w, xc.x, xc.y, xc.z, xc.w};

    // hs = Wx@x_t + Wh@hidden + ht_b
    float hs[30];
#pragma unroll
    for (int j = 0; j < 30; j++) {
      float acc = w[OHTB + j];
#pragma unroll
      for (int k = 0; k < 8; k++) acc = fmaf(w[OWX + j * 8 + k], xr[k], acc);
#pragma unroll
      for (int k = 0; k < 30; k++) acc = fmaf(w[OWH + j * 32 + k], hidden[k], acc);
      hs[j] = acc;
    }
    // a0 = tanh(W0' @ hs + b0)
    float a0[30];
#pragma unroll
    for (int j = 0; j < 30; j++) {
      float acc = w[OB0 + j];
#pragma unroll
      for (int k = 0; k < 30; k++) acc = fmaf(w[OW0 + j * 32 + k], hs[k], acc);
      a0[j] = ftanh(acc);
    }
    // a1 = tanh(W1 @ a0 + b1)
    float a1[45];
#pragma unroll
    for (int j = 0; j < 45; j++) {
      float acc = w[OB1 + j];
#pragma unroll
      for (int k = 0; k < 30; k++) acc = fmaf(w[OW1 + j * 32 + k], a0[k], acc);
      a1[j] = ftanh(acc);
    }
    // a2 = tanh(W2 @ a1 + b2)
    float a2[40];
#pragma unroll
    for (int j = 0; j < 40; j++) {
      float acc = w[OB2 + j];
#pragma unroll
      for (int k = 0; k < 45; k++) acc = fmaf(w[OW2 + j * 48 + k], a1[k], acc);
      a2[j] = ftanh(acc);
    }
    // a3 = tanh(W3 @ a2 + b3)
    float a3[30];
#pragma unroll
    for (int j = 0; j < 30; j++) {
      float acc = w[OB3 + j];
#pragma unroll
      for (int k = 0; k < 40; k++) acc = fmaf(w[OW3 + j * 40 + k], a2[k], acc);
      a3[j] = ftanh(acc);
    }
    // gates + LSTM update (4 fused dot products per cell index)
#pragma unroll
    for (int j = 0; j < 30; j++) {
      float di = w[OGB + j];
      float df = w[OGB + 30 + j];
      float dd = w[OGB + 60 + j];
      float dg = w[OGB + 90 + j];
#pragma unroll
      for (int k = 0; k < 30; k++) {
        float a = a3[k];
        di = fmaf(w[OGW + j * 32 + k], a, di);
        df = fmaf(w[OGW + (30 + j) * 32 + k], a, df);
        dd = fmaf(w[OGW + (60 + j) * 32 + k], a, dd);
        dg = fmaf(w[OGW + (90 + j) * 32 + k], a, dg);
      }
      float ig = fsigm(ftanh(di));
      float fg = fsigm(ftanh(df));
      float og = fsigm(ftanh(dd));
      float gg = ftanh(ftanh(dg));
      float c = fmaf(fg, cell[j], ig * gg);
      cell[j] = c;
      hidden[j] = og * ftanh(c);
    }
  }
  // out = pW @ hidden + pb   (predict heads fused)
  float acc = w[OPB];
#pragma unroll
  for (int k = 0; k < 30; k++) acc = fmaf(w[OPW + k], hidden[k], acc);
  out[b] = acc;
}

extern "C" void kernel_launch(void* const* d_in, const int* in_sizes, int n_in,
                              void* d_out, int out_size, void* d_ws, size_t ws_size,
                              hipStream_t stream) {
  const float* x   = (const float*)d_in[0];
  const float* htW = (const float*)d_in[1];
  const float* htb = (const float*)d_in[2];
  const float* w0  = (const float*)d_in[3];
  const float* b0  = (const float*)d_in[4];
  const float* w1  = (const float*)d_in[5];
  const float* b1  = (const float*)d_in[6];
  const float* w2  = (const float*)d_in[7];
  const float* b2  = (const float*)d_in[8];
  const float* w3  = (const float*)d_in[9];
  const float* b3  = (const float*)d_in[10];
  const float* gw  = (const float*)d_in[11];
  const float* gb  = (const float*)d_in[12];
  const float* p1w = (const float*)d_in[13];
  const float* p1b = (const float*)d_in[14];
  const float* p2w = (const float*)d_in[15];
  const float* p2b = (const float*)d_in[16];
  float* ws = (float*)d_ws;
  float* out = (float*)d_out;

  hipLaunchKernelGGL(prep_kernel, dim3(1), dim3(256), 0, stream,
                     htW, htb, w0, b0, w1, b1, w2, b2, w3, b3, gw, gb,
                     p1w, p1b, p2w, p2b, ws);
  hipLaunchKernelGGL(lstm_main, dim3(NB / 256), dim3(256), 0, stream, x, ws, out);
}

// Round 2
// 7577.469 us; speedup vs baseline: 1.0831x; 1.0831x over previous
//
#include <hip/hip_runtime.h>

// LSTM_26877905338550 — B=1048576 independent tiny-MLP LSTM chains, T=3.
// R2: fix R1's register spills (2 GB scratch traffic, VALUBusy 27%).
//  - cell state lives in LDS (stride 33 -> conflict-free), touched once/t
//  - sched_barrier(0) between layers bounds regalloc live sets
//  - t fully unrolled: t=0 hidden/cell==0 terms constant-fold away

#define NB 1048576

// packed weight offsets (floats), all 16B aligned
#define OWX   0      // Wx   [30][8]
#define OWH   240    // Wh   [30][32] (30 used)
#define OHTB  1200   // ht_b [32]
#define OW0   1232   // W0'  [30][32]
#define OB0   2192   // b0   [32]
#define OW1   2224   // W1   [45][32]
#define OB1   3664   // b1   [48]
#define OW2   3712   // W2   [40][48] (45 used)
#define OB2   5632   // b2   [40]
#define OW3   5672   // W3   [30][40]
#define OB3   6872   // b3   [32]
#define OGW   6904   // gW   [120][32] (30 used)
#define OGB   10744  // gb   [120]
#define OPW   10864  // pW   [32]  (p2@p1 fused)
#define OPB   10896  // pb   scalar

__global__ void prep_kernel(const float* __restrict__ htW, const float* __restrict__ htb,
                            const float* __restrict__ w0,  const float* __restrict__ b0,
                            const float* __restrict__ w1,  const float* __restrict__ b1,
                            const float* __restrict__ w2,  const float* __restrict__ b2,
                            const float* __restrict__ w3,  const float* __restrict__ b3,
                            const float* __restrict__ gw,  const float* __restrict__ gb,
                            const float* __restrict__ p1w, const float* __restrict__ p1b,
                            const float* __restrict__ p2w, const float* __restrict__ p2b,
                            float* __restrict__ ws) {
  int tid = threadIdx.x;
  for (int i = tid; i < 240; i += 256) {            // Wx [30][8]
    int j = i >> 3, k = i & 7;
    ws[OWX + i] = htW[j * 38 + k];
  }
  for (int i = tid; i < 960; i += 256) {            // Wh [30][32]
    int j = i >> 5, k = i & 31;
    ws[OWH + i] = (k < 30) ? htW[j * 38 + 8 + k] : 0.f;
  }
  for (int i = tid; i < 32; i += 256) ws[OHTB + i] = (i < 30) ? htb[i] : 0.f;
  for (int i = tid; i < 960; i += 256) {            // W0' = W0[:, :30] + W0[:, 30:]
    int j = i >> 5, k = i & 31;
    ws[OW0 + i] = (k < 30) ? (w0[j * 60 + k] + w0[j * 60 + 30 + k]) : 0.f;
  }
  for (int i = tid; i < 32; i += 256) ws[OB0 + i] = (i < 30) ? b0[i] : 0.f;
  for (int i = tid; i < 1440; i += 256) {           // W1 [45][32]
    int j = i >> 5, k = i & 31;
    ws[OW1 + i] = (k < 30) ? w1[j * 30 + k] : 0.f;
  }
  for (int i = tid; i < 48; i += 256) ws[OB1 + i] = (i < 45) ? b1[i] : 0.f;
  for (int i = tid; i < 1920; i += 256) {           // W2 [40][48]
    int j = i / 48, k = i % 48;
    ws[OW2 + i] = (k < 45) ? w2[j * 45 + k] : 0.f;
  }
  for (int i = tid; i < 40; i += 256) ws[OB2 + i] = b2[i];
  for (int i = tid; i < 1200; i += 256) {           // W3 [30][40]
    int j = i / 40, k = i % 40;
    ws[OW3 + i] = w3[j * 40 + k];
  }
  for (int i = tid; i < 32; i += 256) ws[OB3 + i] = (i < 30) ? b3[i] : 0.f;
  for (int i = tid; i < 3840; i += 256) {           // gW [120][32]
    int j = i >> 5, k = i & 31;
    ws[OGW + i] = (k < 30) ? gw[j * 30 + k] : 0.f;
  }
  for (int i = tid; i < 120; i += 256) ws[OGB + i] = gb[i];
  for (int i = tid; i < 32; i += 256) {             // pW = p2W @ p1W
    float acc = 0.f;
    if (i < 30)
      for (int m = 0; m < 10; m++) acc += p2w[m] * p1w[m * 30 + i];
    ws[OPW + i] = acc;
  }
  if (tid == 0) {
    float acc = p2b[0];
    for (int m = 0; m < 10; m++) acc += p2w[m] * p1b[m];
    ws[OPB] = acc;
  }
}

__device__ __forceinline__ float ftanh(float v) {
  // tanh(x) = 1 - 2/(exp2(2x*log2e)+1); saturates correctly via inf/0
  float u = __builtin_amdgcn_exp2f(v * 2.8853900817779268f);
  return 1.0f - 2.0f * __builtin_amdgcn_rcpf(u + 1.0f);
}
__device__ __forceinline__ float fsigm(float v) {
  float u = __builtin_amdgcn_exp2f(v * -1.4426950408889634f);
  return __builtin_amdgcn_rcpf(1.0f + u);
}

#define SBAR() __builtin_amdgcn_sched_barrier(0)

__global__ __launch_bounds__(256, 2) void lstm_main(const float* __restrict__ x,
                                                    const float* __restrict__ w,
                                                    float* __restrict__ out) {
  // cell state in LDS: stride 33 floats/thread -> bank = (tid + j) % 32, conflict-free
  __shared__ float cellLds[256 * 33];
  int tid = threadIdx.x;
  int b = blockIdx.x * 256 + tid;
  const float* xb = x + (size_t)b * 24;

  float hidden[30];
#pragma unroll
  for (int j = 0; j < 30; j++) hidden[j] = 0.f;

#pragma unroll
  for (int t = 0; t < 3; t++) {
    float4 xa = *(const float4*)(xb + t * 8);
    float4 xc = *(const float4*)(xb + t * 8 + 4);
    float xr[8] = {xa.x, xa.y, xa.z, xa.w, xc.x, xc.y, xc.z, xc.w};

    // hs = Wx@x_t + Wh@hidden + ht_b   (t=0: hidden==0, Wh term folds away)
    float hs[30];
#pragma unroll
    for (int j = 0; j < 30; j++) {
      float acc = w[OHTB + j];
#pragma unroll
      for (int k = 0; k < 8; k++) acc = fmaf(w[OWX + j * 8 + k], xr[k], acc);
      if (t > 0) {
#pragma unroll
        for (int k = 0; k < 30; k++) acc = fmaf(w[OWH + j * 32 + k], hidden[k], acc);
      }
      hs[j] = acc;
    }
    SBAR();
    // a0 = tanh(W0' @ hs + b0)
    float a0[30];
#pragma unroll
    for (int j = 0; j < 30; j++) {
      float acc = w[OB0 + j];
#pragma unroll
      for (int k = 0; k < 30; k++) acc = fmaf(w[OW0 + j * 32 + k], hs[k], acc);
      a0[j] = ftanh(acc);
    }
    SBAR();
    // a1 = tanh(W1 @ a0 + b1)
    float a1[45];
#pragma unroll
    for (int j = 0; j < 45; j++) {
      float acc = w[OB1 + j];
#pragma unroll
      for (int k = 0; k < 30; k++) acc = fmaf(w[OW1 + j * 32 + k], a0[k], acc);
      a1[j] = ftanh(acc);
    }
    SBAR();
    // a2 = tanh(W2 @ a1 + b2)
    float a2[40];
#pragma unroll
    for (int j = 0; j < 40; j++) {
      float acc = w[OB2 + j];
#pragma unroll
      for (int k = 0; k < 45; k++) acc = fmaf(w[OW2 + j * 48 + k], a1[k], acc);
      a2[j] = ftanh(acc);
    }
    SBAR();
    // a3 = tanh(W3 @ a2 + b3)
    float a3[30];
#pragma unroll
    for (int j = 0; j < 30; j++) {
      float acc = w[OB3 + j];
#pragma unroll
      for (int k = 0; k < 40; k++) acc = fmaf(w[OW3 + j * 40 + k], a2[k], acc);
      a3[j] = ftanh(acc);
    }
    SBAR();
    // gates + LSTM update (4 fused dot products per cell index)
#pragma unroll
    for (int j = 0; j < 30; j++) {
      float di = w[OGB + j];
      float df = w[OGB + 30 + j];
      float dd = w[OGB + 60 + j];
      float dg = w[OGB + 90 + j];
#pragma unroll
      for (int k = 0; k < 30; k++) {
        float a = a3[k];
        di = fmaf(w[OGW + j * 32 + k], a, di);
        df = fmaf(w[OGW + (30 + j) * 32 + k], a, df);
        dd = fmaf(w[OGW + (60 + j) * 32 + k], a, dd);
        dg = fmaf(w[OGW + (90 + j) * 32 + k], a, dg);
      }
      float ig = fsigm(ftanh(di));
      float fg = fsigm(ftanh(df));
      float og = fsigm(ftanh(dd));
      float gg = ftanh(ftanh(dg));
      float cprev = (t == 0) ? 0.f : cellLds[tid * 33 + j];  // t=0 folds
      float c = fmaf(fg, cprev, ig * gg);
      if (t < 2) cellLds[tid * 33 + j] = c;                  // last t: no store needed
      hidden[j] = og * ftanh(c);
    }
    SBAR();
  }
  // out = pW @ hidden + pb   (predict heads fused)
  float acc = w[OPB];
#pragma unroll
  for (int k = 0; k < 30; k++) acc = fmaf(w[OPW + k], hidden[k], acc);
  out[b] = acc;
}

extern "C" void kernel_launch(void* const* d_in, const int* in_sizes, int n_in,
                              void* d_out, int out_size, void* d_ws, size_t ws_size,
                              hipStream_t stream) {
  const float* x   = (const float*)d_in[0];
  const float* htW = (const float*)d_in[1];
  const float* htb = (const float*)d_in[2];
  const float* w0  = (const float*)d_in[3];
  const float* b0  = (const float*)d_in[4];
  const float* w1  = (const float*)d_in[5];
  const float* b1  = (const float*)d_in[6];
  const float* w2  = (const float*)d_in[7];
  const float* b2  = (const float*)d_in[8];
  const float* w3  = (const float*)d_in[9];
  const float* b3  = (const float*)d_in[10];
  const float* gw  = (const float*)d_in[11];
  const float* gb  = (const float*)d_in[12];
  const float* p1w = (const float*)d_in[13];
  const float* p1b = (const float*)d_in[14];
  const float* p2w = (const float*)d_in[15];
  const float* p2b = (const float*)d_in[16];
  float* ws = (float*)d_ws;
  float* out = (float*)d_out;

  hipLaunchKernelGGL(prep_kernel, dim3(1), dim3(256), 0, stream,
                     htW, htb, w0, b0, w1, b1, w2, b2, w3, b3, gw, gb,
                     p1w, p1b, p2w, p2b, ws);
  hipLaunchKernelGGL(lstm_main, dim3(NB / 256), dim3(256), 0, stream, x, ws, out);
}

// Round 3
// 1077.582 us; speedup vs baseline: 7.6163x; 7.0319x over previous
//
#include <hip/hip_runtime.h>

// LSTM_26877905338550 — B=1048576 independent tiny-MLP LSTM chains, T=3.
// R3: weights staged to LDS; all weight reads are uniform ds_read_b128
// broadcasts (1 instr / 4 FMAs, ~no LDS BW). cell+hidden in registers,
// sched_barrier(0) every 8 outputs bounds live sets. t-loop NOT unrolled
// (I$); t=0 dead work skipped via uniform branch.

#define NB 1048576

// packed weight offsets (floats), all 16B aligned
#define OWX   0      // Wx   [30][8]
#define OWH   240    // Wh   [30][32] (30 used)
#define OHTB  1200   // ht_b [32]
#define OW0   1232   // W0'  [30][32]
#define OB0   2192   // b0   [32]
#define OW1   2224   // W1   [45][32]
#define OB1   3664   // b1   [48]
#define OW2   3712   // W2   [40][48] (45 used)
#define OB2   5632   // b2   [40]
#define OW3   5672   // W3   [30][40]
#define OB3   6872   // b3   [32]
#define OGW   6904   // gW   [120][32] (30 used)
#define OGB   10744  // gb   [120]
#define OPW   10864  // pW   [32]  (p2@p1 fused)
#define OPB   10896  // pb   scalar
#define WTOT  10912  // padded to float4 multiple

__global__ void prep_kernel(const float* __restrict__ htW, const float* __restrict__ htb,
                            const float* __restrict__ w0,  const float* __restrict__ b0,
                            const float* __restrict__ w1,  const float* __restrict__ b1,
                            const float* __restrict__ w2,  const float* __restrict__ b2,
                            const float* __restrict__ w3,  const float* __restrict__ b3,
                            const float* __restrict__ gw,  const float* __restrict__ gb,
                            const float* __restrict__ p1w, const float* __restrict__ p1b,
                            const float* __restrict__ p2w, const float* __restrict__ p2b,
                            float* __restrict__ ws) {
  int tid = threadIdx.x;
  for (int i = tid; i < 240; i += 256) {            // Wx [30][8]
    int j = i >> 3, k = i & 7;
    ws[OWX + i] = htW[j * 38 + k];
  }
  for (int i = tid; i < 960; i += 256) {            // Wh [30][32]
    int j = i >> 5, k = i & 31;
    ws[OWH + i] = (k < 30) ? htW[j * 38 + 8 + k] : 0.f;
  }
  for (int i = tid; i < 32; i += 256) ws[OHTB + i] = (i < 30) ? htb[i] : 0.f;
  for (int i = tid; i < 960; i += 256) {            // W0' = W0[:, :30] + W0[:, 30:]
    int j = i >> 5, k = i & 31;
    ws[OW0 + i] = (k < 30) ? (w0[j * 60 + k] + w0[j * 60 + 30 + k]) : 0.f;
  }
  for (int i = tid; i < 32; i += 256) ws[OB0 + i] = (i < 30) ? b0[i] : 0.f;
  for (int i = tid; i < 1440; i += 256) {           // W1 [45][32]
    int j = i >> 5, k = i & 31;
    ws[OW1 + i] = (k < 30) ? w1[j * 30 + k] : 0.f;
  }
  for (int i = tid; i < 48; i += 256) ws[OB1 + i] = (i < 45) ? b1[i] : 0.f;
  for (int i = tid; i < 1920; i += 256) {           // W2 [40][48]
    int j = i / 48, k = i % 48;
    ws[OW2 + i] = (k < 45) ? w2[j * 45 + k] : 0.f;
  }
  for (int i = tid; i < 40; i += 256) ws[OB2 + i] = b2[i];
  for (int i = tid; i < 1200; i += 256) {           // W3 [30][40]
    int j = i / 40, k = i % 40;
    ws[OW3 + i] = w3[j * 40 + k];
  }
  for (int i = tid; i < 32; i += 256) ws[OB3 + i] = (i < 30) ? b3[i] : 0.f;
  for (int i = tid; i < 3840; i += 256) {           // gW [120][32]
    int j = i >> 5, k = i & 31;
    ws[OGW + i] = (k < 30) ? gw[j * 30 + k] : 0.f;
  }
  for (int i = tid; i < 120; i += 256) ws[OGB + i] = gb[i];
  for (int i = tid; i < 32; i += 256) {             // pW = p2W @ p1W
    float acc = 0.f;
    if (i < 30)
      for (int m = 0; m < 10; m++) acc += p2w[m] * p1w[m * 30 + i];
    ws[OPW + i] = acc;
  }
  for (int i = tid; i < WTOT - 10897; i += 256) ws[10897 + i] = 0.f;  // pad
  if (tid == 0) {
    float acc = p2b[0];
    for (int m = 0; m < 10; m++) acc += p2w[m] * p1b[m];
    ws[OPB] = acc;
  }
}

__device__ __forceinline__ float ftanh(float v) {
  float u = __builtin_amdgcn_exp2f(v * 2.8853900817779268f);
  return 1.0f - 2.0f * __builtin_amdgcn_rcpf(u + 1.0f);
}
__device__ __forceinline__ float fsigm(float v) {
  float u = __builtin_amdgcn_exp2f(v * -1.4426950408889634f);
  return __builtin_amdgcn_rcpf(1.0f + u);
}

#define SBAR() __builtin_amdgcn_sched_barrier(0)

// out[j] = (TANH? tanh : id)(sum_k W[woff + j*STRIDE + k] * in[k] + W[boff + j])
template <int OUT, int IN, int STRIDE, bool TANH>
__device__ __forceinline__ void layer(const float* Wl, int woff, int boff,
                                      const float* in, float* outv) {
  constexpr int K4 = IN / 4;
#pragma unroll
  for (int j = 0; j < OUT; j++) {
    float acc = Wl[boff + j];
#pragma unroll
    for (int k4 = 0; k4 < K4; k4++) {
      float4 wv = *(const float4*)&Wl[woff + j * STRIDE + k4 * 4];
      acc = fmaf(wv.x, in[k4 * 4 + 0], acc);
      acc = fmaf(wv.y, in[k4 * 4 + 1], acc);
      acc = fmaf(wv.z, in[k4 * 4 + 2], acc);
      acc = fmaf(wv.w, in[k4 * 4 + 3], acc);
    }
    if constexpr ((IN & 3) >= 2) {
      float2 wv = *(const float2*)&Wl[woff + j * STRIDE + K4 * 4];
      acc = fmaf(wv.x, in[K4 * 4 + 0], acc);
      acc = fmaf(wv.y, in[K4 * 4 + 1], acc);
      if constexpr ((IN & 3) == 3)
        acc = fmaf(Wl[woff + j * STRIDE + K4 * 4 + 2], in[K4 * 4 + 2], acc);
    } else if constexpr ((IN & 3) == 1) {
      acc = fmaf(Wl[woff + j * STRIDE + K4 * 4], in[K4 * 4], acc);
    }
    outv[j] = TANH ? ftanh(acc) : acc;
    if ((j & 7) == 7) SBAR();
  }
}

__global__ __launch_bounds__(256, 3) void lstm_main(const float* __restrict__ x,
                                                    const float* __restrict__ w,
                                                    float* __restrict__ out) {
  __shared__ __align__(16) float Wl[WTOT];
  int tid = threadIdx.x;
  for (int i = tid; i < WTOT / 4; i += 256)
    ((float4*)Wl)[i] = ((const float4*)w)[i];
  __syncthreads();

  int b = blockIdx.x * 256 + tid;
  const float* xb = x + (size_t)b * 24;

  float hidden[30], cell[30];
#pragma unroll
  for (int j = 0; j < 30; j++) { hidden[j] = 0.f; cell[j] = 0.f; }

  for (int t = 0; t < 3; t++) {  // NOT unrolled: keep code small (I$)
    float4 xa = *(const float4*)(xb + t * 8);
    float4 xc = *(const float4*)(xb + t * 8 + 4);

    // hs = Wx@x_t + Wh@hidden + ht_b  (t=0: skip Wh, hidden==0)
    float hs[30];
#pragma unroll
    for (int j = 0; j < 30; j++) {
      float acc = Wl[OHTB + j];
      float4 wa = *(const float4*)&Wl[OWX + j * 8];
      float4 wc = *(const float4*)&Wl[OWX + j * 8 + 4];
      acc = fmaf(wa.x, xa.x, acc);
      acc = fmaf(wa.y, xa.y, acc);
      acc = fmaf(wa.z, xa.z, acc);
      acc = fmaf(wa.w, xa.w, acc);
      acc = fmaf(wc.x, xc.x, acc);
      acc = fmaf(wc.y, xc.y, acc);
      acc = fmaf(wc.z, xc.z, acc);
      acc = fmaf(wc.w, xc.w, acc);
      if (t > 0) {
#pragma unroll
        for (int k4 = 0; k4 < 7; k4++) {
          float4 wv = *(const float4*)&Wl[OWH + j * 32 + k4 * 4];
          acc = fmaf(wv.x, hidden[k4 * 4 + 0], acc);
          acc = fmaf(wv.y, hidden[k4 * 4 + 1], acc);
          acc = fmaf(wv.z, hidden[k4 * 4 + 2], acc);
          acc = fmaf(wv.w, hidden[k4 * 4 + 3], acc);
        }
        float2 wv = *(const float2*)&Wl[OWH + j * 32 + 28];
        acc = fmaf(wv.x, hidden[28], acc);
        acc = fmaf(wv.y, hidden[29], acc);
      }
      hs[j] = acc;
      if ((j & 7) == 7) SBAR();
    }
    SBAR();
    float a0[30];
    layer<30, 30, 32, true>(Wl, OW0, OB0, hs, a0);
    SBAR();
    float a1[45];
    layer<45, 30, 32, true>(Wl, OW1, OB1, a0, a1);
    SBAR();
    float a2[40];
    layer<40, 45, 48, true>(Wl, OW2, OB2, a1, a2);
    SBAR();
    float a3[30];
    layer<30, 40, 40, true>(Wl, OW3, OB3, a2, a3);
    SBAR();
    // gates + LSTM update
#pragma unroll
    for (int j = 0; j < 30; j++) {
      float d0 = Wl[OGB + j];
      float d1 = Wl[OGB + 30 + j];
      float d2 = Wl[OGB + 60 + j];
      float d3 = Wl[OGB + 90 + j];
#pragma unroll
      for (int k4 = 0; k4 < 7; k4++) {
        float4 wi = *(const float4*)&Wl[OGW + (j)*32 + k4 * 4];
        float4 wf = *(const float4*)&Wl[OGW + (30 + j) * 32 + k4 * 4];
        float4 wo = *(const float4*)&Wl[OGW + (60 + j) * 32 + k4 * 4];
        float4 wg = *(const float4*)&Wl[OGW + (90 + j) * 32 + k4 * 4];
#pragma unroll
        for (int q = 0; q < 4; q++) {
          float a = a3[k4 * 4 + q];
          d0 = fmaf(q == 0 ? wi.x : q == 1 ? wi.y : q == 2 ? wi.z : wi.w, a, d0);
          d1 = fmaf(q == 0 ? wf.x : q == 1 ? wf.y : q == 2 ? wf.z : wf.w, a, d1);
          d2 = fmaf(q == 0 ? wo.x : q == 1 ? wo.y : q == 2 ? wo.z : wo.w, a, d2);
          d3 = fmaf(q == 0 ? wg.x : q == 1 ? wg.y : q == 2 ? wg.z : wg.w, a, d3);
        }
      }
      {
        float2 wi = *(const float2*)&Wl[OGW + (j)*32 + 28];
        float2 wf = *(const float2*)&Wl[OGW + (30 + j) * 32 + 28];
        float2 wo = *(const float2*)&Wl[OGW + (60 + j) * 32 + 28];
        float2 wg = *(const float2*)&Wl[OGW + (90 + j) * 32 + 28];
        d0 = fmaf(wi.x, a3[28], d0); d0 = fmaf(wi.y, a3[29], d0);
        d1 = fmaf(wf.x, a3[28], d1); d1 = fmaf(wf.y, a3[29], d1);
        d2 = fmaf(wo.x, a3[28], d2); d2 = fmaf(wo.y, a3[29], d2);
        d3 = fmaf(wg.x, a3[28], d3); d3 = fmaf(wg.y, a3[29], d3);
      }
      float ig = fsigm(ftanh(d0));
      float fg = fsigm(ftanh(d1));
      float og = fsigm(ftanh(d2));
      float gg = ftanh(ftanh(d3));
      float c = fmaf(fg, cell[j], ig * gg);  // t=0: cell==0, exact
      cell[j] = c;
      hidden[j] = og * ftanh(c);
      if ((j & 3) == 3) SBAR();
    }
    SBAR();
  }
  // out = pW @ hidden + pb
  float acc = Wl[OPB];
#pragma unroll
  for (int k = 0; k < 30; k++) acc = fmaf(Wl[OPW + k], hidden[k], acc);
  out[b] = acc;
}

extern "C" void kernel_launch(void* const* d_in, const int* in_sizes, int n_in,
                              void* d_out, int out_size, void* d_ws, size_t ws_size,
                              hipStream_t stream) {
  const float* x   = (const float*)d_in[0];
  const float* htW = (const float*)d_in[1];
  const float* htb = (const float*)d_in[2];
  const float* w0  = (const float*)d_in[3];
  const float* b0  = (const float*)d_in[4];
  const float* w1  = (const float*)d_in[5];
  const float* b1  = (const float*)d_in[6];
  const float* w2  = (const float*)d_in[7];
  const float* b2  = (const float*)d_in[8];
  const float* w3  = (const float*)d_in[9];
  const float* b3  = (const float*)d_in[10];
  const float* gw  = (const float*)d_in[11];
  const float* gb  = (const float*)d_in[12];
  const float* p1w = (const float*)d_in[13];
  const float* p1b = (const float*)d_in[14];
  const float* p2w = (const float*)d_in[15];
  const float* p2b = (const float*)d_in[16];
  float* ws = (float*)d_ws;
  float* out = (float*)d_out;

  hipLaunchKernelGGL(prep_kernel, dim3(1), dim3(256), 0, stream,
                     htW, htb, w0, b0, w1, b1, w2, b2, w3, b3, gw, gb,
                     p1w, p1b, p2w, p2b, ws);
  hipLaunchKernelGGL(lstm_main, dim3(NB / 256), dim3(256), 0, stream, x, ws, out);
}